// Round 2
// baseline (986.632 us; speedup 1.0000x reference)
//
#include <hip/hip_runtime.h>

#define NN 50000
#define HD 8
#define CD 64
#define NHF 512   // HD*CD

// ---------------- CSR build (by destination) ----------------
__global__ void k_init_cnt(int* __restrict__ cnt) {
    int i = blockIdx.x * 256 + threadIdx.x;
    if (i < NN) cnt[i] = 1;  // self loop contributes 1 per node
}

__global__ void k_hist(const int* __restrict__ dst, int E, int* __restrict__ cnt) {
    int e = blockIdx.x * 256 + threadIdx.x;
    if (e < E) atomicAdd(&cnt[dst[e]], 1);
}

// cnt and cursor may alias: cnt[i] is read into a local before cursor[i] is written.
__global__ __launch_bounds__(1024) void k_scan(const int* __restrict__ cnt_in,
                                               int* __restrict__ row_ptr,
                                               int* __restrict__ cursor,
                                               int* __restrict__ csr_src) {
    __shared__ int sums[1024];
    const int tid = threadIdx.x;
    const int chunk = (NN + 1023) / 1024;  // 49
    int start = tid * chunk;
    int end = min(start + chunk, NN);
    if (start > NN) start = NN;
    int s = 0;
    for (int i = start; i < end; ++i) s += cnt_in[i];
    sums[tid] = s;
    __syncthreads();
    for (int off = 1; off < 1024; off <<= 1) {
        int v = (tid >= off) ? sums[tid - off] : 0;
        __syncthreads();
        sums[tid] += v;
        __syncthreads();
    }
    int base = tid ? sums[tid - 1] : 0;
    for (int i = start; i < end; ++i) {
        int c = cnt_in[i];     // read BEFORE aliased cursor write
        row_ptr[i] = base;
        csr_src[base] = i;     // self-loop occupies first slot of each segment
        cursor[i] = base + 1;
        base += c;
    }
    if (tid == 1023) row_ptr[NN] = base;  // = E + NN
}

__global__ void k_scatter(const int* __restrict__ src, const int* __restrict__ dst,
                          int E, int* __restrict__ cursor, int* __restrict__ csr_src) {
    int e = blockIdx.x * 256 + threadIdx.x;
    if (e < E) {
        int pos = atomicAdd(&cursor[dst[e]], 1);
        csr_src[pos] = src[e];
    }
}

// ---------------- GEMM (f32, 64x64 tile, 4x4/thread) + fused alpha epilogue ----------------
__global__ __launch_bounds__(256) void k_gemm_alpha(
    const float* __restrict__ A, const float* __restrict__ B,
    const float* __restrict__ a_src, const float* __restrict__ a_dst,
    float* __restrict__ C, float* __restrict__ asrc_out, float* __restrict__ adst_out,
    int M, int K)
{
    __shared__ float As[16][64];
    __shared__ float Bs[16][64];
    const int t  = threadIdx.x;
    const int bm = blockIdx.x * 64;
    const int bn = blockIdx.y * 64;
    const int tm = (t >> 4) * 4;
    const int tn = (t & 15) * 4;

    float acc[4][4] = {};

    const int a_row = bm + (t >> 2);
    const int a_kv  = (t & 3) * 4;
    const int b_k   = (t >> 4);
    const int b_col = bn + (t & 15) * 4;

    for (int k0 = 0; k0 < K; k0 += 16) {
        float4 av = make_float4(0.f, 0.f, 0.f, 0.f);
        if (a_row < M) av = *(const float4*)(A + (size_t)a_row * K + k0 + a_kv);
        As[a_kv + 0][t >> 2] = av.x;
        As[a_kv + 1][t >> 2] = av.y;
        As[a_kv + 2][t >> 2] = av.z;
        As[a_kv + 3][t >> 2] = av.w;
        float4 bv = *(const float4*)(B + (size_t)(k0 + b_k) * NHF + b_col);
        *(float4*)(&Bs[b_k][(t & 15) * 4]) = bv;
        __syncthreads();
#pragma unroll
        for (int kk = 0; kk < 16; ++kk) {
            float4 a = *(const float4*)(&As[kk][tm]);
            float4 b = *(const float4*)(&Bs[kk][tn]);
            acc[0][0] += a.x * b.x; acc[0][1] += a.x * b.y; acc[0][2] += a.x * b.z; acc[0][3] += a.x * b.w;
            acc[1][0] += a.y * b.x; acc[1][1] += a.y * b.y; acc[1][2] += a.y * b.z; acc[1][3] += a.y * b.w;
            acc[2][0] += a.z * b.x; acc[2][1] += a.z * b.y; acc[2][2] += a.z * b.z; acc[2][3] += a.z * b.w;
            acc[3][0] += a.w * b.x; acc[3][1] += a.w * b.y; acc[3][2] += a.w * b.z; acc[3][3] += a.w * b.w;
        }
        __syncthreads();
    }

    const float4 asv = *(const float4*)(a_src + bn + tn);
    const float4 adv = *(const float4*)(a_dst + bn + tn);
    const int head = bn >> 6;
#pragma unroll
    for (int i = 0; i < 4; ++i) {
        int row = bm + tm + i;
        float4 cv = make_float4(acc[i][0], acc[i][1], acc[i][2], acc[i][3]);
        if (row < M) *(float4*)(C + (size_t)row * NHF + bn + tn) = cv;
        float ps = cv.x * asv.x + cv.y * asv.y + cv.z * asv.z + cv.w * asv.w;
        float pd = cv.x * adv.x + cv.y * adv.y + cv.z * adv.z + cv.w * adv.w;
#pragma unroll
        for (int off = 1; off < 16; off <<= 1) {
            ps += __shfl_xor(ps, off);
            pd += __shfl_xor(pd, off);
        }
        if ((t & 15) == 0 && row < M) {
            asrc_out[row * HD + head] = ps;
            adst_out[row * HD + head] = pd;
        }
    }
}

// ---------------- fused edge softmax + aggregation: one wave per dst node ----------------
// 4-edge software pipeline: all index loads, then all gathers, then the (order-
// preserving) online-softmax updates. Amortizes the dependent-load chain 4x.
__global__ __launch_bounds__(256) void k_aggregate(
    const float* __restrict__ xl, const float* __restrict__ asrc,
    const float* __restrict__ adst, const int* __restrict__ row_ptr,
    const int* __restrict__ csr_src, const float* __restrict__ bias,
    float* __restrict__ out, int relu)
{
    __shared__ float sh[4][NHF];
    const int wid  = threadIdx.x >> 6;
    const int lane = threadIdx.x & 63;
    const int n    = blockIdx.x * 4 + wid;   // NN % 4 == 0, always valid
    const int head = lane >> 3;

    const float ad = adst[n * HD + head];
    const int e0 = row_ptr[n];
    const int e1 = row_ptr[n + 1];

    float m = -1e30f, s = 0.f;
    float acc[8] = {};

#define ONLINE(araw, vA, vB)                                        \
    {                                                               \
        float a_ = (araw) > 0.f ? (araw) : 0.2f * (araw);           \
        float mn_ = fmaxf(m, a_);                                   \
        float r_ = __expf(m - mn_);                                 \
        float p_ = __expf(a_ - mn_);                                \
        m = mn_;                                                    \
        s = s * r_ + p_;                                            \
        acc[0] = acc[0] * r_ + p_ * vA.x;                           \
        acc[1] = acc[1] * r_ + p_ * vA.y;                           \
        acc[2] = acc[2] * r_ + p_ * vA.z;                           \
        acc[3] = acc[3] * r_ + p_ * vA.w;                           \
        acc[4] = acc[4] * r_ + p_ * vB.x;                           \
        acc[5] = acc[5] * r_ + p_ * vB.y;                           \
        acc[6] = acc[6] * r_ + p_ * vB.z;                           \
        acc[7] = acc[7] * r_ + p_ * vB.w;                           \
    }

    for (int base = e0; base < e1; base += 4) {
        const int rem = e1 - base;
        // phase 0: edge src indices (wave-uniform, sequential -> scalar loads)
        int s0 = csr_src[base];
        int s1 = (rem > 1) ? csr_src[base + 1] : 0;
        int s2 = (rem > 2) ? csr_src[base + 2] : 0;
        int s3 = (rem > 3) ? csr_src[base + 3] : 0;
        // phase 1: issue all gathers back-to-back
        float a0, a1 = 0.f, a2 = 0.f, a3 = 0.f;
        float4 u0, u1, w0, w1, y0, y1, z0, z1;
        a0 = asrc[s0 * HD + head] + ad;
        { const float4* rp = (const float4*)(xl + (size_t)s0 * NHF + lane * 8); u0 = rp[0]; u1 = rp[1]; }
        if (rem > 1) {
            a1 = asrc[s1 * HD + head] + ad;
            const float4* rp = (const float4*)(xl + (size_t)s1 * NHF + lane * 8); w0 = rp[0]; w1 = rp[1];
        }
        if (rem > 2) {
            a2 = asrc[s2 * HD + head] + ad;
            const float4* rp = (const float4*)(xl + (size_t)s2 * NHF + lane * 8); y0 = rp[0]; y1 = rp[1];
        }
        if (rem > 3) {
            a3 = asrc[s3 * HD + head] + ad;
            const float4* rp = (const float4*)(xl + (size_t)s3 * NHF + lane * 8); z0 = rp[0]; z1 = rp[1];
        }
        // phase 2: in-order online updates (numerics identical to scalar loop)
        ONLINE(a0, u0, u1);
        if (rem > 1) ONLINE(a1, w0, w1);
        if (rem > 2) ONLINE(a2, y0, y1);
        if (rem > 3) ONLINE(a3, z0, z1);
    }
#undef ONLINE

    const float inv = 1.f / (s + 1e-16f);
#pragma unroll
    for (int j = 0; j < 8; ++j) sh[wid][lane * 8 + j] = acc[j] * inv;
    __syncthreads();

    float sum = 0.f;
#pragma unroll
    for (int h = 0; h < HD; ++h) sum += sh[wid][h * CD + lane];
    float res = sum * 0.125f + bias[lane];
    if (relu) res = fmaxf(res, 0.f);
    out[(size_t)n * CD + lane] = res;
}

// ---------------- launch ----------------
extern "C" void kernel_launch(void* const* d_in, const int* in_sizes, int n_in,
                              void* d_out, int out_size, void* d_ws, size_t ws_size,
                              hipStream_t stream) {
    const float* x   = (const float*)d_in[0];
    const int*   ei  = (const int*)d_in[1];
    const float* W1  = (const float*)d_in[2];
    const float* as1 = (const float*)d_in[3];
    const float* ad1 = (const float*)d_in[4];
    const float* b1  = (const float*)d_in[5];
    const float* W2  = (const float*)d_in[6];
    const float* as2 = (const float*)d_in[7];
    const float* ad2 = (const float*)d_in[8];
    const float* b2  = (const float*)d_in[9];

    const int E = in_sizes[1] / 2;      // 800000
    const int* esrc = ei;
    const int* edst = ei + E;

    char* ws = (char*)d_ws;
    float* xl      = (float*)ws;                            // 102,400,000 B
    float* asrc    = (float*)(ws + 102400000);              // 1,600,000 B
    float* adst    = (float*)(ws + 104000000);              // 1,600,000 B
    float* h       = (float*)(ws + 105600000);              // 12,800,000 B
    int*   row_ptr = (int*)  (ws + 118400000);              // 200,004 B
    int*   cursor  = (int*)  (ws + 118600004);              // 200,000 B
    int*   csr_src = (int*)  (ws + 118800004);              // 3,400,000 B

    k_init_cnt<<<(NN + 255) / 256, 256, 0, stream>>>(cursor);
    k_hist<<<(E + 255) / 256, 256, 0, stream>>>(edst, E, cursor);
    k_scan<<<1, 1024, 0, stream>>>(cursor, row_ptr, cursor, csr_src);
    k_scatter<<<(E + 255) / 256, 256, 0, stream>>>(esrc, edst, E, cursor, csr_src);

    dim3 gemm_grid((NN + 63) / 64, NHF / 64);

    k_gemm_alpha<<<gemm_grid, 256, 0, stream>>>(x, W1, as1, ad1, xl, asrc, adst, NN, 256);
    k_aggregate<<<NN / 4, 256, 0, stream>>>(xl, asrc, adst, row_ptr, csr_src, b1, h, 1);

    k_gemm_alpha<<<gemm_grid, 256, 0, stream>>>(h, W2, as2, ad2, xl, asrc, adst, NN, 64);
    k_aggregate<<<NN / 4, 256, 0, stream>>>(xl, asrc, adst, row_ptr, csr_src, b2, (float*)d_out, 0);
}

// Round 3
// 826.324 us; speedup vs baseline: 1.1940x; 1.1940x over previous
//
#include <hip/hip_runtime.h>

#define NN 50000
#define HD 8
#define CD 64
#define NHF 512   // HD*CD

typedef __attribute__((ext_vector_type(8))) short short8v;
typedef __attribute__((ext_vector_type(8))) unsigned short us8;
typedef __attribute__((ext_vector_type(4))) unsigned short us4;
typedef __attribute__((ext_vector_type(4))) float f32x4;

__device__ inline unsigned short f32_to_bf16(float f) {
    unsigned int u = __float_as_uint(f);
    unsigned int r = (u + 0x7fffu + ((u >> 16) & 1u)) >> 16;
    return (unsigned short)r;
}
__device__ inline float bf16_to_f32(unsigned short h) {
    return __uint_as_float(((unsigned int)h) << 16);
}

// ---------------- CSR build (by destination) ----------------
__global__ void k_init_cnt(int* __restrict__ cnt) {
    int i = blockIdx.x * 256 + threadIdx.x;
    if (i < NN) cnt[i] = 1;  // self loop contributes 1 per node
}

__global__ void k_hist(const int* __restrict__ dst, int E, int* __restrict__ cnt) {
    int e = blockIdx.x * 256 + threadIdx.x;
    if (e < E) atomicAdd(&cnt[dst[e]], 1);
}

// cnt and cursor may alias: cnt[i] is read into a local before cursor[i] is written.
__global__ __launch_bounds__(1024) void k_scan(const int* __restrict__ cnt_in,
                                               int* __restrict__ row_ptr,
                                               int* __restrict__ cursor,
                                               int* __restrict__ csr_src) {
    __shared__ int sums[1024];
    const int tid = threadIdx.x;
    const int chunk = (NN + 1023) / 1024;  // 49
    int start = tid * chunk;
    int end = min(start + chunk, NN);
    if (start > NN) start = NN;
    int s = 0;
    for (int i = start; i < end; ++i) s += cnt_in[i];
    sums[tid] = s;
    __syncthreads();
    for (int off = 1; off < 1024; off <<= 1) {
        int v = (tid >= off) ? sums[tid - off] : 0;
        __syncthreads();
        sums[tid] += v;
        __syncthreads();
    }
    int base = tid ? sums[tid - 1] : 0;
    for (int i = start; i < end; ++i) {
        int c = cnt_in[i];     // read BEFORE aliased cursor write
        row_ptr[i] = base;
        csr_src[base] = i;     // self-loop occupies first slot of each segment
        cursor[i] = base + 1;
        base += c;
    }
    if (tid == 1023) row_ptr[NN] = base;  // = E + NN
}

__global__ void k_scatter(const int* __restrict__ src, const int* __restrict__ dst,
                          int E, int* __restrict__ cursor, int* __restrict__ csr_src) {
    int e = blockIdx.x * 256 + threadIdx.x;
    if (e < E) {
        int pos = atomicAdd(&cursor[dst[e]], 1);
        csr_src[pos] = src[e];
    }
}

// ---------------- B split + transpose: B[K][512] f32 -> Bt_hi/Bt_lo [512][K] bf16 ----------------
__global__ void k_split_bt(const float* __restrict__ B, unsigned short* __restrict__ bht,
                           unsigned short* __restrict__ blt, int K) {
    int idx = blockIdx.x * 256 + threadIdx.x;
    if (idx < K * NHF) {
        int k = idx >> 9, n = idx & 511;
        float v = B[idx];
        unsigned short hb = f32_to_bf16(v);
        float l = v - bf16_to_f32(hb);
        unsigned short lb = f32_to_bf16(l);
        bht[n * K + k] = hb;
        blt[n * K + k] = lb;
    }
}

// ---------------- split-bf16 MFMA GEMM + fused alpha epilogue ----------------
// C = Ah*Bh + Ah*Bl + Al*Bh (f32 accumulate). A is f32, split hi/lo during LDS staging.
// Tile 128x128, 4 waves (2x2), each wave 64x64 via 4x4 16x16x32 MFMA fragments.
#define BM 128
#define BN 128
#define BKF 32
#define LDK 40   // padded LDS row stride in ushort (80 B: 16B-aligned, 2-way bank alias only)

__global__ __launch_bounds__(256) void k_gemm_mfma(
    const float* __restrict__ A,        // [M][K] f32
    const unsigned short* __restrict__ Bht,  // [512][K] bf16 (n-major)
    const unsigned short* __restrict__ Blt,
    const float* __restrict__ a_src, const float* __restrict__ a_dst,
    float* __restrict__ C, float* __restrict__ asrc_out, float* __restrict__ adst_out,
    int M, int K)
{
    __shared__ unsigned short Ash[BM][LDK];
    __shared__ unsigned short Asl[BM][LDK];
    __shared__ unsigned short Bsh[BN][LDK];
    __shared__ unsigned short Bsl[BN][LDK];

    const int t = threadIdx.x;
    const int lane = t & 63;
    const int wid = t >> 6;
    const int wr = wid >> 1, wc = wid & 1;
    const int bm = blockIdx.x * BM;
    const int bn = blockIdx.y * BN;
    const int l15 = lane & 15;
    const int lg = lane >> 4;       // 0..3

    f32x4 acc[4][4];
#pragma unroll
    for (int mi = 0; mi < 4; ++mi)
#pragma unroll
        for (int ni = 0; ni < 4; ++ni)
            acc[mi][ni] = (f32x4){0.f, 0.f, 0.f, 0.f};

    const int srow = t >> 1;         // 0..127
    const int skc = (t & 1) * 16;    // 0 or 16

    for (int k0 = 0; k0 < K; k0 += BKF) {
        __syncthreads();
        // stage A: read 16 f32, split to hi/lo bf16
        {
            const int gr = bm + srow;
            if (gr < M) {
                const float* ga = A + (size_t)gr * K + k0 + skc;
#pragma unroll
                for (int c = 0; c < 16; c += 4) {
                    float4 v = *(const float4*)(ga + c);
                    us4 hs, ls;
                    hs.x = f32_to_bf16(v.x); ls.x = f32_to_bf16(v.x - bf16_to_f32(hs.x));
                    hs.y = f32_to_bf16(v.y); ls.y = f32_to_bf16(v.y - bf16_to_f32(hs.y));
                    hs.z = f32_to_bf16(v.z); ls.z = f32_to_bf16(v.z - bf16_to_f32(hs.z));
                    hs.w = f32_to_bf16(v.w); ls.w = f32_to_bf16(v.w - bf16_to_f32(hs.w));
                    *(us4*)&Ash[srow][skc + c] = hs;
                    *(us4*)&Asl[srow][skc + c] = ls;
                }
            } else {
                us4 z = (us4){0, 0, 0, 0};
#pragma unroll
                for (int c = 0; c < 16; c += 4) {
                    *(us4*)&Ash[srow][skc + c] = z;
                    *(us4*)&Asl[srow][skc + c] = z;
                }
            }
            // stage B: already split bf16, 16B vector loads
            const unsigned short* gbh = Bht + (size_t)(bn + srow) * K + k0 + skc;
            const unsigned short* gbl = Blt + (size_t)(bn + srow) * K + k0 + skc;
            *(us8*)&Bsh[srow][skc] = *(const us8*)gbh;
            *(us8*)&Bsh[srow][skc + 8] = *(const us8*)(gbh + 8);
            *(us8*)&Bsl[srow][skc] = *(const us8*)gbl;
            *(us8*)&Bsl[srow][skc + 8] = *(const us8*)(gbl + 8);
        }
        __syncthreads();

        short8v ah[4], al[4], bh[4], bl[4];
#pragma unroll
        for (int i = 0; i < 4; ++i) {
            ah[i] = *(const short8v*)&Ash[wr * 64 + i * 16 + l15][lg * 8];
            al[i] = *(const short8v*)&Asl[wr * 64 + i * 16 + l15][lg * 8];
            bh[i] = *(const short8v*)&Bsh[wc * 64 + i * 16 + l15][lg * 8];
            bl[i] = *(const short8v*)&Bsl[wc * 64 + i * 16 + l15][lg * 8];
        }
#pragma unroll
        for (int mi = 0; mi < 4; ++mi)
#pragma unroll
            for (int ni = 0; ni < 4; ++ni) {
                acc[mi][ni] = __builtin_amdgcn_mfma_f32_16x16x32_bf16(ah[mi], bh[ni], acc[mi][ni], 0, 0, 0);
                acc[mi][ni] = __builtin_amdgcn_mfma_f32_16x16x32_bf16(ah[mi], bl[ni], acc[mi][ni], 0, 0, 0);
                acc[mi][ni] = __builtin_amdgcn_mfma_f32_16x16x32_bf16(al[mi], bh[ni], acc[mi][ni], 0, 0, 0);
            }
    }

    // epilogue: C store + per-row alpha dots (each wave's 64 cols = one head)
    const int head_w = (bn >> 6) + wc;
    float ca[4], cd[4];
#pragma unroll
    for (int ni = 0; ni < 4; ++ni) {
        ca[ni] = a_src[head_w * 64 + ni * 16 + l15];
        cd[ni] = a_dst[head_w * 64 + ni * 16 + l15];
    }
#pragma unroll
    for (int mi = 0; mi < 4; ++mi) {
#pragma unroll
        for (int r = 0; r < 4; ++r) {
            int row = bm + wr * 64 + mi * 16 + lg * 4 + r;
            float ps = 0.f, pd = 0.f;
#pragma unroll
            for (int ni = 0; ni < 4; ++ni) {
                float cv = acc[mi][ni][r];
                int col = bn + wc * 64 + ni * 16 + l15;
                if (row < M) C[(size_t)row * NHF + col] = cv;
                ps += cv * ca[ni];
                pd += cv * cd[ni];
            }
#pragma unroll
            for (int off = 1; off < 16; off <<= 1) {
                ps += __shfl_xor(ps, off);
                pd += __shfl_xor(pd, off);
            }
            if (l15 == 0 && row < M) {
                asrc_out[row * HD + head_w] = ps;
                adst_out[row * HD + head_w] = pd;
            }
        }
    }
}

// ---------------- fused edge softmax + aggregation: one wave per dst node ----------------
// Branchless 4-edge batches (loads unconditional -> compiler keeps them in flight),
// scalar tail peel. Update order identical to the scalar loop.
__global__ __launch_bounds__(256) void k_aggregate(
    const float* __restrict__ xl, const float* __restrict__ asrc,
    const float* __restrict__ adst, const int* __restrict__ row_ptr,
    const int* __restrict__ csr_src, const float* __restrict__ bias,
    float* __restrict__ out, int relu)
{
    __shared__ float sh[4][NHF];
    const int wid = threadIdx.x >> 6;
    const int lane = threadIdx.x & 63;
    const int n = blockIdx.x * 4 + wid;   // NN % 4 == 0
    const int head = lane >> 3;

    const float ad = adst[n * HD + head];
    const int e0 = row_ptr[n];
    const int e1 = row_ptr[n + 1];

    float m = -1e30f, s = 0.f;
    float acc[8] = {};

#define ONLINE(araw, vA, vB)                                        \
    {                                                               \
        float a_ = (araw) > 0.f ? (araw) : 0.2f * (araw);           \
        float mn_ = fmaxf(m, a_);                                   \
        float r_ = __expf(m - mn_);                                 \
        float p_ = __expf(a_ - mn_);                                \
        m = mn_;                                                    \
        s = s * r_ + p_;                                            \
        acc[0] = acc[0] * r_ + p_ * vA.x;                           \
        acc[1] = acc[1] * r_ + p_ * vA.y;                           \
        acc[2] = acc[2] * r_ + p_ * vA.z;                           \
        acc[3] = acc[3] * r_ + p_ * vA.w;                           \
        acc[4] = acc[4] * r_ + p_ * vB.x;                           \
        acc[5] = acc[5] * r_ + p_ * vB.y;                           \
        acc[6] = acc[6] * r_ + p_ * vB.z;                           \
        acc[7] = acc[7] * r_ + p_ * vB.w;                           \
    }

    int e = e0;
    for (; e + 4 <= e1; e += 4) {
        int s0 = csr_src[e];
        int s1 = csr_src[e + 1];
        int s2 = csr_src[e + 2];
        int s3 = csr_src[e + 3];
        float a0 = asrc[s0 * HD + head];
        float a1 = asrc[s1 * HD + head];
        float a2 = asrc[s2 * HD + head];
        float a3 = asrc[s3 * HD + head];
        const float4* r0 = (const float4*)(xl + (size_t)s0 * NHF + lane * 8);
        const float4* r1 = (const float4*)(xl + (size_t)s1 * NHF + lane * 8);
        const float4* r2 = (const float4*)(xl + (size_t)s2 * NHF + lane * 8);
        const float4* r3 = (const float4*)(xl + (size_t)s3 * NHF + lane * 8);
        float4 u0 = r0[0], u1 = r0[1];
        float4 w0 = r1[0], w1 = r1[1];
        float4 y0 = r2[0], y1 = r2[1];
        float4 z0 = r3[0], z1 = r3[1];
        ONLINE(a0 + ad, u0, u1);
        ONLINE(a1 + ad, w0, w1);
        ONLINE(a2 + ad, y0, y1);
        ONLINE(a3 + ad, z0, z1);
    }
    for (; e < e1; ++e) {
        int s0 = csr_src[e];
        float a0 = asrc[s0 * HD + head] + ad;
        const float4* rp = (const float4*)(xl + (size_t)s0 * NHF + lane * 8);
        float4 u0 = rp[0], u1 = rp[1];
        ONLINE(a0, u0, u1);
    }
#undef ONLINE

    const float inv = 1.f / (s + 1e-16f);
#pragma unroll
    for (int j = 0; j < 8; ++j) sh[wid][lane * 8 + j] = acc[j] * inv;
    __syncthreads();

    float sum = 0.f;
#pragma unroll
    for (int h = 0; h < HD; ++h) sum += sh[wid][h * CD + lane];
    float res = sum * 0.125f + bias[lane];
    if (relu) res = fmaxf(res, 0.f);
    out[(size_t)n * CD + lane] = res;
}

// ---------------- launch ----------------
extern "C" void kernel_launch(void* const* d_in, const int* in_sizes, int n_in,
                              void* d_out, int out_size, void* d_ws, size_t ws_size,
                              hipStream_t stream) {
    const float* x   = (const float*)d_in[0];
    const int*   ei  = (const int*)d_in[1];
    const float* W1  = (const float*)d_in[2];
    const float* as1 = (const float*)d_in[3];
    const float* ad1 = (const float*)d_in[4];
    const float* b1  = (const float*)d_in[5];
    const float* W2  = (const float*)d_in[6];
    const float* as2 = (const float*)d_in[7];
    const float* ad2 = (const float*)d_in[8];
    const float* b2  = (const float*)d_in[9];

    const int E = in_sizes[1] / 2;      // 800000
    const int* esrc = ei;
    const int* edst = ei + E;

    char* ws = (char*)d_ws;
    float* xl      = (float*)ws;                              // 102,400,000 B
    float* asrc    = (float*)(ws + 102400000);                // 1,600,000 B
    float* adst    = (float*)(ws + 104000000);                // 1,600,000 B
    float* h       = (float*)(ws + 105600000);                // 12,800,000 B
    int*   row_ptr = (int*)  (ws + 118400000);                // 200,004 B
    int*   cursor  = (int*)  (ws + 118600192);                // 200,000 B
    int*   csr_src = (int*)  (ws + 118800384);                // 3,400,000 B
    unsigned short* Bht1 = (unsigned short*)(ws + 122200832); // 262,144 B
    unsigned short* Blt1 = (unsigned short*)(ws + 122463232); // 262,144 B
    unsigned short* Bht2 = (unsigned short*)(ws + 122725632); // 65,536 B
    unsigned short* Blt2 = (unsigned short*)(ws + 122791424); // 65,536 B

    // CSR build (shared by both layers)
    k_init_cnt<<<(NN + 255) / 256, 256, 0, stream>>>(cursor);
    k_hist<<<(E + 255) / 256, 256, 0, stream>>>(edst, E, cursor);
    k_scan<<<1, 1024, 0, stream>>>(cursor, row_ptr, cursor, csr_src);
    k_scatter<<<(E + 255) / 256, 256, 0, stream>>>(esrc, edst, E, cursor, csr_src);

    // weight splits (tiny)
    k_split_bt<<<(256 * NHF + 255) / 256, 256, 0, stream>>>(W1, Bht1, Blt1, 256);
    k_split_bt<<<(64 * NHF + 255) / 256, 256, 0, stream>>>(W2, Bht2, Blt2, 64);

    dim3 gemm_grid((NN + BM - 1) / BM, NHF / BN);

    k_gemm_mfma<<<gemm_grid, 256, 0, stream>>>(x, Bht1, Blt1, as1, ad1, xl, asrc, adst, NN, 256);
    k_aggregate<<<NN / 4, 256, 0, stream>>>(xl, asrc, adst, row_ptr, csr_src, b1, h, 1);

    k_gemm_mfma<<<gemm_grid, 256, 0, stream>>>(h, Bht2, Blt2, as2, ad2, xl, asrc, adst, NN, 64);
    k_aggregate<<<NN / 4, 256, 0, stream>>>(xl, asrc, adst, row_ptr, csr_src, b2, (float*)d_out, 0);
}